// Round 1
// baseline (2176.346 us; speedup 1.0000x reference)
//
#include <hip/hip_runtime.h>
#include <math.h>

#define HD 128
#define NBR 8
#define LSTEPS 64
#define TILE_B 64
#define HT_PAD 68     // hT row stride (floats): keeps float4 alignment; broadcast reads anyway
#define PART_PAD 65   // logit-partial row stride: 65b%32 = b%32 -> 2-way (free)

// workspace layout (floats)
#define WPT_OFF   0        // w_hh permuted-transposed: [k][4*hh+q] = w_hh[q*128+hh][k]   (128*512)
#define WIPT_OFF  65536    // w_ih same layout                                            (128*512)
#define PP_OFF    131072   // P = w_emb@w_ih^T, layout [j][q][hh]                          (8*512)
#define BIH_OFF   135168   // b_ih permuted [q][hh]                                        (512)
#define BHH_OFF   135680   // b_hh permuted [q][hh]                                        (512)
// total ws: 136192 floats = 544768 bytes

__global__ __launch_bounds__(256) void setup_kernel(
    const float* __restrict__ w_emb, const float* __restrict__ w_ih,
    const float* __restrict__ w_hh, const float* __restrict__ b_ih,
    const float* __restrict__ b_hh, float* __restrict__ ws)
{
  int tid = blockIdx.x * blockDim.x + threadIdx.x;
  if (tid < 65536) {
    int k = tid >> 9, col = tid & 511;
    int hh = col >> 2, q = col & 3;
    ws[WPT_OFF + tid]  = w_hh[(q*HD + hh)*HD + k];
    ws[WIPT_OFF + tid] = w_ih[(q*HD + hh)*HD + k];
  }
  if (tid < 4096) {
    int j = tid >> 9, rem = tid & 511;
    int q = rem >> 7, hh2 = rem & 127;
    const float* wr = w_ih + (q*HD + hh2)*HD;
    const float* er = w_emb + j*HD;
    float s = 0.f;
    for (int k = 0; k < HD; ++k) s = fmaf(er[k], wr[k], s);
    ws[PP_OFF + (size_t)j*512 + q*HD + hh2] = s;
  }
  if (tid < 512) {
    int q = tid >> 7, hh2 = tid & 127;
    ws[BIH_OFF + tid] = b_ih[q*HD + hh2];
    ws[BHH_OFF + tid] = b_hh[q*HD + hh2];
  }
}

__global__ __launch_bounds__(512, 2) void ctrl_kernel(
    const int* __restrict__ class_ids,
    const float* __restrict__ gumbel_u,
    const float* __restrict__ g_emb,
    const float* __restrict__ w_soft,
    const float* __restrict__ ws,
    float* __restrict__ out,
    int Btot)
{
  __shared__ float hT[HD * HT_PAD];          // h transposed: [k][b], 34816 B
  __shared__ float wsoft_l[NBR * HD];        // 4096 B
  __shared__ float part_l[TILE_B * PART_PAD];// 16640 B
  __shared__ int   br_l[TILE_B];             // 256 B    (total ~55.8 KB < 64 KB)

  const int tid = threadIdx.x;
  const int b0  = blockIdx.x * TILE_B;
  const size_t BL = (size_t)Btot * LSTEPS;

  const float* __restrict__ wpT  = ws + WPT_OFF;
  const float* __restrict__ wipT = ws + WIPT_OFF;
  const float* __restrict__ Pp   = ws + PP_OFF;

  for (int i = tid; i < NBR*HD; i += 512) wsoft_l[i] = w_soft[i];

  const int hh = tid & 127;   // hidden index (gate quadrant row)
  const int bg = tid >> 7;    // batch group 0..3 (16 batches each)

  float bi[4], bh[4];
  #pragma unroll
  for (int q = 0; q < 4; ++q) {
    bi[q] = ws[BIH_OFF + q*HD + hh];
    bh[q] = ws[BHH_OFF + q*HD + hh];
  }

  // ---- stage x0^T = g_emb[class_ids]^T into hT ----
  {
    int sb = tid >> 3;        // 0..63 batch
    int kc = tid & 7;         // k-chunk of 16
    int cid = class_ids[b0 + sb];
    const float* src = g_emb + (size_t)cid * HD + kc*16;
    #pragma unroll
    for (int ii = 0; ii < 4; ++ii) {
      float4 v = *(const float4*)(src + 4*ii);
      int kb = kc*16 + 4*ii;
      hT[(kb+0)*HT_PAD + sb] = v.x;
      hT[(kb+1)*HT_PAD + sb] = v.y;
      hT[(kb+2)*HT_PAD + sb] = v.z;
      hT[(kb+3)*HT_PAD + sb] = v.w;
    }
  }
  __syncthreads();

  // ---- q0 = x0 @ w_ih^T (permuted), kept in registers for all 64 steps ----
  float q0[4][16];
  #pragma unroll
  for (int q = 0; q < 4; ++q)
    #pragma unroll
    for (int j = 0; j < 16; ++j) q0[q][j] = 0.f;

  #pragma unroll 2
  for (int k = 0; k < HD; ++k) {
    float4 w = *(const float4*)(wipT + k*512 + 4*hh);
    const float* hr = &hT[k*HT_PAD + bg*16];
    float4 ha = *(const float4*)(hr);
    float4 hb2 = *(const float4*)(hr+4);
    float4 hc = *(const float4*)(hr+8);
    float4 hd = *(const float4*)(hr+12);
    float hv[16] = {ha.x,ha.y,ha.z,ha.w,hb2.x,hb2.y,hb2.z,hb2.w,
                    hc.x,hc.y,hc.z,hc.w,hd.x,hd.y,hd.z,hd.w};
    float wv[4] = {w.x,w.y,w.z,w.w};
    #pragma unroll
    for (int q = 0; q < 4; ++q)
      #pragma unroll
      for (int j = 0; j < 16; ++j)
        q0[q][j] = fmaf(hv[j], wv[q], q0[q][j]);
  }
  __syncthreads();

  float c[16];
  #pragma unroll
  for (int j = 0; j < 16; ++j) c[j] = 0.f;

  for (int t = 0; t < LSTEPS; ++t) {
    // prefetch gumbel u for this step (overlaps GEMM)
    float4 ua = make_float4(0,0,0,0), ub = make_float4(0,0,0,0);
    if (tid < TILE_B) {
      const float* up = gumbel_u + ((size_t)t * Btot + (b0 + tid)) * NBR;
      ua = *(const float4*)up;
      ub = *(const float4*)(up + 4);
    }

    // ---- GEMM: acc = h @ w_hh^T (skipped at t=0 since h0 = 0) ----
    float acc[4][16];
    #pragma unroll
    for (int q = 0; q < 4; ++q)
      #pragma unroll
      for (int j = 0; j < 16; ++j) acc[q][j] = 0.f;

    if (t > 0) {
      #pragma unroll 2
      for (int k = 0; k < HD; ++k) {
        float4 w = *(const float4*)(wpT + k*512 + 4*hh);
        const float* hr = &hT[k*HT_PAD + bg*16];
        float4 ha = *(const float4*)(hr);
        float4 hb2 = *(const float4*)(hr+4);
        float4 hc = *(const float4*)(hr+8);
        float4 hd = *(const float4*)(hr+12);
        float hv[16] = {ha.x,ha.y,ha.z,ha.w,hb2.x,hb2.y,hb2.z,hb2.w,
                        hc.x,hc.y,hc.z,hc.w,hd.x,hd.y,hd.z,hd.w};
        float wv[4] = {w.x,w.y,w.z,w.w};
        #pragma unroll
        for (int q = 0; q < 4; ++q)
          #pragma unroll
          for (int j = 0; j < 16; ++j)
            acc[q][j] = fmaf(hv[j], wv[q], acc[q][j]);
      }
    }

    // ---- combine x-part + bias, LSTM pointwise (registers only) ----
    float h2v[16];
    #pragma unroll
    for (int j = 0; j < 16; ++j) {
      float xw[4];
      if (t == 0) {
        #pragma unroll
        for (int q = 0; q < 4; ++q) xw[q] = q0[q][j];
      } else {
        int br = br_l[bg*16 + j];
        const float* pr = Pp + (size_t)br*512 + hh;
        #pragma unroll
        for (int q = 0; q < 4; ++q) xw[q] = 0.5f * (pr[q*HD] + q0[q][j]);
      }
      float gi = ((xw[0] + acc[0][j]) + bi[0]) + bh[0];
      float gf = ((xw[1] + acc[1][j]) + bi[1]) + bh[1];
      float gg = ((xw[2] + acc[2][j]) + bi[2]) + bh[2];
      float go = ((xw[3] + acc[3][j]) + bi[3]) + bh[3];
      float iv = 1.f/(1.f + expf(-gi));
      float fv = 1.f/(1.f + expf(-gf));
      float gv = tanhf(gg);
      float ov = 1.f/(1.f + expf(-go));
      float c2 = fv*c[j] + iv*gv;
      c[j] = c2;
      h2v[j] = ov * tanhf(c2);
    }
    __syncthreads();   // (A) all hT reads of this step done before overwrite

    {
      float* dst = &hT[hh*HT_PAD + bg*16];
      *(float4*)(dst)    = make_float4(h2v[0],h2v[1],h2v[2],h2v[3]);
      *(float4*)(dst+4)  = make_float4(h2v[4],h2v[5],h2v[6],h2v[7]);
      *(float4*)(dst+8)  = make_float4(h2v[8],h2v[9],h2v[10],h2v[11]);
      *(float4*)(dst+12) = make_float4(h2v[12],h2v[13],h2v[14],h2v[15]);
    }
    __syncthreads();   // (B) new h visible

    // ---- logit partials: thread (lb = tid&63, ch = tid>>6), 16-k chunk each ----
    {
      int lb = tid & 63, ch = tid >> 6;
      float part[8];
      #pragma unroll
      for (int nb = 0; nb < 8; ++nb) part[nb] = 0.f;
      #pragma unroll
      for (int i = 0; i < 16; ++i) {
        float hvv = hT[(ch*16 + i)*HT_PAD + lb];
        #pragma unroll
        for (int nb = 0; nb < 8; ++nb)
          part[nb] = fmaf(hvv, wsoft_l[nb*HD + ch*16 + i], part[nb]);
      }
      #pragma unroll
      for (int nb = 0; nb < 8; ++nb)
        part_l[lb*PART_PAD + nb*8 + ch] = part[nb];
    }
    __syncthreads();   // (C)

    // ---- sampling: one thread per batch row ----
    if (tid < TILE_B) {
      int lb = tid;
      float lg[8];
      #pragma unroll
      for (int nb = 0; nb < 8; ++nb) {
        float s = 0.f;
        #pragma unroll
        for (int ch = 0; ch < 8; ++ch) s += part_l[lb*PART_PAD + nb*8 + ch];
        lg[nb] = 2.5f * tanhf(s / 5.0f);
      }
      float uv[8] = {ua.x,ua.y,ua.z,ua.w,ub.x,ub.y,ub.z,ub.w};
      int br = 0; float best;
      {
        float uc = fminf(fmaxf(uv[0], 1e-8f), 0.99999999f);
        best = lg[0] - logf(-logf(uc));
      }
      #pragma unroll
      for (int nb = 1; nb < 8; ++nb) {
        float uc = fminf(fmaxf(uv[nb], 1e-8f), 0.99999999f);
        float y = lg[nb] - logf(-logf(uc));
        if (y > best) { best = y; br = nb; }   // strict >  == first-occurrence argmax
      }
      float m = lg[0];
      #pragma unroll
      for (int nb = 1; nb < 8; ++nb) m = fmaxf(m, lg[nb]);
      float se = 0.f;
      #pragma unroll
      for (int nb = 0; nb < 8; ++nb) se += expf(lg[nb] - m);
      float lse = logf(se);
      float lp = (lg[br] - m) - lse;
      float ent = 0.f;
      #pragma unroll
      for (int nb = 0; nb < 8; ++nb) {
        float lpi = (lg[nb] - m) - lse;
        ent -= expf(lpi) * lpi;
      }
      size_t row = (size_t)(b0 + lb) * LSTEPS + t;
      out[row]        = (float)br;
      out[BL + row]   = lp;
      out[2*BL + row] = ent;
      out[3*BL + row] = expf(lp);
      br_l[lb] = br;
    }
    __syncthreads();   // (E) br_l visible for next step's combine
  }
}

extern "C" void kernel_launch(void* const* d_in, const int* in_sizes, int n_in,
                              void* d_out, int out_size, void* d_ws, size_t ws_size,
                              hipStream_t stream) {
  const int*   class_ids = (const int*)d_in[0];
  const float* gumbel_u  = (const float*)d_in[1];
  const float* g_emb     = (const float*)d_in[2];
  const float* w_emb     = (const float*)d_in[3];
  const float* w_soft    = (const float*)d_in[4];
  const float* w_ih      = (const float*)d_in[5];
  const float* w_hh      = (const float*)d_in[6];
  const float* b_ih      = (const float*)d_in[7];
  const float* b_hh      = (const float*)d_in[8];
  float* out = (float*)d_out;
  float* ws  = (float*)d_ws;
  int B = in_sizes[0];

  hipLaunchKernelGGL(setup_kernel, dim3(256), dim3(256), 0, stream,
                     w_emb, w_ih, w_hh, b_ih, b_hh, ws);
  hipLaunchKernelGGL(ctrl_kernel, dim3(B / TILE_B), dim3(512), 0, stream,
                     class_ids, gumbel_u, g_emb, w_soft, ws, out, B);
}